// Round 6
// baseline (6586.522 us; speedup 1.0000x reference)
//
#include <hip/hip_runtime.h>
#include <hip/hip_bf16.h>

typedef _Float16 f16;
typedef __attribute__((ext_vector_type(8))) _Float16 f16x8;
typedef __attribute__((ext_vector_type(4))) float f32x4;
typedef __attribute__((ext_vector_type(4))) unsigned int u32x4;

#define TT 128

__device__ __forceinline__ float sigmoidf_(float x) { return 1.0f / (1.0f + __expf(-x)); }

__device__ __forceinline__ unsigned pack2h_(float a, float b) {
  union { f16 h; unsigned short u; } x, y;
  x.h = (f16)a; y.h = (f16)b;
  return (unsigned)x.u | ((unsigned)y.u << 16);
}

// ---------------------------------------------------------------------------
// fp32 -> fp16 convert (n multiple of 4)
__global__ __launch_bounds__(256) void k_f2h(const float* __restrict__ in,
                                             f16* __restrict__ out, long n4) {
  long i = (long)blockIdx.x * 256 + threadIdx.x;
  if (i >= n4) return;
  float4 v = ((const float4*)in)[i];
  out[i*4+0] = (f16)v.x; out[i*4+1] = (f16)v.y;
  out[i*4+2] = (f16)v.z; out[i*4+3] = (f16)v.w;
}

// gather rule_emb rows for init_prod -> fp16 (32 x 1024)
__global__ __launch_bounds__(256) void k_gather_prod(const float* __restrict__ rule_emb,
                                                     const int* __restrict__ init_prod,
                                                     f16* __restrict__ out) {
  int i = blockIdx.x * 256 + threadIdx.x;
  int b = i >> 10, k = i & 1023;
  out[i] = (f16)rule_emb[(long)init_prod[b] * 1024 + k];
}

// poison n dwords with 0xFFFFFFFF (f16 -NaN halves; tanh path never makes it)
__global__ __launch_bounds__(256) void k_poison(unsigned int* __restrict__ p, long n) {
  long i = (long)blockIdx.x * 256 + threadIdx.x;
  if (i < n) p[i] = 0xFFFFFFFFu;
}

__global__ __launch_bounds__(256) void k_zero(int* __restrict__ p, int n) {
  int i = blockIdx.x * 256 + threadIdx.x;
  if (i < n) p[i] = 0;
}

// h0 -> fp16 into st slot 0. st layout: [t][b 32][j 1024]
__global__ __launch_bounds__(256) void k_h0(const float* __restrict__ h0,
                                            f16* __restrict__ st) {
  int i = blockIdx.x * 256 + threadIdx.x;
  st[i] = (f16)h0[i];
}

// (B, L=512, H=1024) fp32 -> outT (B, H, L) f16  AND  outN (B, L, H) f16
__global__ __launch_bounds__(256) void k_transpose(const float* __restrict__ in,
                                                   f16* __restrict__ outT,
                                                   f16* __restrict__ outN) {
  __shared__ float tile[32][33];
  const int b  = blockIdx.z;
  const int l0 = blockIdx.x * 32, h0 = blockIdx.y * 32;
  in   += (long)b * 512 * 1024;
  outT += (long)b * 1024 * 512;
  outN += (long)b * 512 * 1024;
  const int c = threadIdx.x & 31, r = threadIdx.x >> 5;
#pragma unroll
  for (int p = 0; p < 4; ++p) {
    float v = in[(long)(l0 + r + p*8) * 1024 + h0 + c];
    tile[r + p*8][c] = v;
    outN[(long)(l0 + r + p*8) * 1024 + h0 + c] = (f16)v;
  }
  __syncthreads();
#pragma unroll
  for (int p = 0; p < 4; ++p)
    outT[(long)(h0 + r + p*8) * 512 + l0 + c] = (f16)tile[c][r + p*8];
}

// ---------------------------------------------------------------------------
// fp16 MFMA GEMM: C[M,N] = act( A[M,K] @ B[N,K]^T + bias1 + bias2 )
// 128x128 tile, BK=32, register-prefetch double buffer.
// bmod: B K-index wraps mod bmod. zdiv: split-K, partials at outF+slice*sSl.
// ilv: outF column remap col -> (col&1023)*4 + (col>>10)  (gate-interleave).
__global__ __launch_bounds__(256) void k_gemm(
    const f16* __restrict__ A, long lda, long sA,
    const f16* __restrict__ B, long ldb, long sB,
    float* __restrict__ outF, long ldF, long sF, long sSl,
    f16* __restrict__ outH, long ldH, long sH,
    f16* __restrict__ outH2, long ldH2, long sH2,
    f16* __restrict__ out2, long ld2, long s2,
    const float* __restrict__ bias1, const float* __restrict__ bias2,
    int M, int N, int K, int act, int bmod, int zdiv, int ilv)
{
  __shared__ __align__(16) f16 As[128][40];
  __shared__ __align__(16) f16 Bs[128][40];
  const int tid = threadIdx.x;
  const int w = tid >> 6, lane = tid & 63;
  const int wm = (w & 1) * 64, wn = (w >> 1) * 64;
  const int lr = lane >> 4, lc = lane & 15;
  const long m0 = (long)blockIdx.x * 128;
  const long n0 = (long)blockIdx.y * 128;
  int z = blockIdx.z, batch = z, slice = 0, Ks = K;
  if (zdiv > 1) { batch = z / zdiv; slice = z - batch * zdiv; Ks = K / zdiv; }
  const long kbeg = (long)slice * Ks;
  A += (long)batch * sA;
  B += (long)batch * sB;

  const int rr = tid >> 2, sg = (tid & 3) * 8;
  const int nIt = Ks / 32;

  uint4 pa[2], pb[2];
  {
    long k = kbeg;
    long kb = bmod ? (k & (bmod - 1)) : k;
#pragma unroll
    for (int p = 0; p < 2; ++p) {
      int row = p * 64 + rr;
      uint4 va = {0,0,0,0}, vb = {0,0,0,0};
      if (m0 + row < M) va = *(const uint4*)(A + (m0 + row) * lda + k + sg);
      if (n0 + row < N) vb = *(const uint4*)(B + (n0 + row) * ldb + kb + sg);
      pa[p] = va; pb[p] = vb;
    }
  }

  f32x4 acc[4][4];
#pragma unroll
  for (int i = 0; i < 4; ++i)
#pragma unroll
    for (int j = 0; j < 4; ++j) { f32x4 zz = {0.f,0.f,0.f,0.f}; acc[i][j] = zz; }

  for (int it = 0; it < nIt; ++it) {
#pragma unroll
    for (int p = 0; p < 2; ++p) {
      *(uint4*)&As[p * 64 + rr][sg] = pa[p];
      *(uint4*)&Bs[p * 64 + rr][sg] = pb[p];
    }
    __syncthreads();
    if (it + 1 < nIt) {
      long k = kbeg + (long)(it + 1) * 32;
      long kb = bmod ? (k & (bmod - 1)) : k;
#pragma unroll
      for (int p = 0; p < 2; ++p) {
        int row = p * 64 + rr;
        uint4 va = {0,0,0,0}, vb = {0,0,0,0};
        if (m0 + row < M) va = *(const uint4*)(A + (m0 + row) * lda + k + sg);
        if (n0 + row < N) vb = *(const uint4*)(B + (n0 + row) * ldb + kb + sg);
        pa[p] = va; pb[p] = vb;
      }
    }
    f16x8 af[4], bf[4];
#pragma unroll
    for (int i = 0; i < 4; ++i) af[i] = *(const f16x8*)&As[wm + i*16 + lc][lr * 8];
#pragma unroll
    for (int j = 0; j < 4; ++j) bf[j] = *(const f16x8*)&Bs[wn + j*16 + lc][lr * 8];
#pragma unroll
    for (int i = 0; i < 4; ++i)
#pragma unroll
      for (int j = 0; j < 4; ++j)
        acc[i][j] = __builtin_amdgcn_mfma_f32_16x16x32_f16(af[i], bf[j], acc[i][j], 0, 0, 0);
    __syncthreads();
  }

  if (outF)  outF  += (long)batch * sF + (long)slice * sSl;
  if (outH)  outH  += (long)batch * sH;
  if (outH2) outH2 += (long)batch * sH2;
  if (out2)  out2  += (long)batch * s2;
#pragma unroll
  for (int i = 0; i < 4; ++i)
#pragma unroll
    for (int j = 0; j < 4; ++j)
#pragma unroll
      for (int r = 0; r < 4; ++r) {
        long row = m0 + wm + i * 16 + lr * 4 + r;
        long col = n0 + wn + j * 16 + lc;
        if (row < M && col < N) {
          float v = acc[i][j][r];
          if (bias1) v += bias1[col];
          if (bias2) v += bias2[col];
          if (act)   v = tanhf(v);
          if (outF) {
            long fc = ilv ? ((col & 1023) * 4 + (col >> 10)) : col;
            outF[row * ldF + fc] = v;
          }
          if (outH)  outH[row * ldH + col] = (f16)v;
          if (outH2) outH2[row * ldH2 + col] = (f16)v;
          if (out2) {
            f16 hi = (f16)v;
            out2[row * ld2 + col]        = hi;
            out2[row * ld2 + 1024 + col] = (f16)(v - (float)hi);
          }
        }
      }
}

// ---------------------------------------------------------------------------
// Persistent LSTM, XCD-LOCAL dataflow. The recurrence is batch-independent,
// so batches are partitioned across XCDs: all producers/consumers of a batch
// share one per-XCD L2 (coherence point ~200cy away instead of the Infinity
// Fabric ~900cy that R1-R5 all paid; they converged at ~3.9us/step).
//
// Placement: 256 blocks x 512 thr; LDS forced >80KB => exactly 1 block/CU =>
// HW-guaranteed 32 blocks per XCD. Each block reads its physical XCD via
// s_getreg(HW_REG_XCC_ID) and ranks itself 0..31 with a per-XCD atomic.
// Block (xcd, rank) owns batches 4*xcd..+4 x h-cols 32*rank..+32 (= 128
// gate rows). W_hh slice held in REGISTERS (32 f16x8, pinned live by
// keep-alive asm each iteration - R5's 112-VGPR sink fix).
//
// Protocol (intra-XCD): producers publish packed dwords with plain
// write-through stores (sc0, fire-and-forget). Consumers poison-poll the
// DATA directly with sc0 (L1-bypass, L2-served) loads until no 16-bit half
// is 0xFFFF (f16 -NaN; h=o*tanh(c) never produces it). One L2 round trip,
// no flags, no vmcnt ack, nothing touches the IF. Escalation: after 4096
// failed polls a wave switches to device-scope (sc0 sc1) loads, bounding
// the worst case if the intra-XCD coherence model is wrong (no hangs).
// M=4 real batches pad the 16-row MFMA tile: rows 4-15 duplicate rows 0-3
// (same lane addresses coalesce; duplicate outputs are ignored).
__global__ __launch_bounds__(512, 2) void k_lstm_all(
    const f16* __restrict__ Whh,          // (4096,1024) fp16
    const float* __restrict__ nt_table,   // (200,1024,4) gate-interleaved
    const float* __restrict__ prod_gates, // (32,1024,4) gate-interleaved
    const int* __restrict__ nt_ids,       // (128,32)
    const float* __restrict__ c0,         // (32,1024)
    f16* __restrict__ st,                 // (129,32,1024) [t][b][j]; 1.. poisoned
    f16* __restrict__ q2,                 // (4096,2048) hi|lo
    f16* __restrict__ X,                  // (4096,3072)
    f16* __restrict__ Y1,                 // (4096,2048)
    int* __restrict__ cnt)                // 8 ints: per-XCD rank counters
{
  __shared__ float partial[2][8][4][32][5];   // [buf][wave][gate][col][b(4)+pad]
  __shared__ char lds_pad[49152];             // force 1 block/CU (total ~90KB)
  __shared__ int sh_xcd, sh_rank;
  const int tid = threadIdx.x;
  const int w = tid >> 6, lane = tid & 63;    // wave = K-chunk owner (128 K)
  const int lr = lane >> 4, lc = lane & 15;

  if (tid == 0) {
    unsigned xr;
    asm volatile("s_getreg_b32 %0, hwreg(HW_REG_XCC_ID)" : "=s"(xr));
    sh_xcd = (int)(xr & 7);
    sh_rank = __hip_atomic_fetch_add(&cnt[xr & 7], 1,
                                     __ATOMIC_RELAXED, __HIP_MEMORY_SCOPE_AGENT);
    ((volatile char*)lds_pad)[0] = 1;   // keep pad allocated
  }
  __syncthreads();
  const int xcd = sh_xcd, rank = sh_rank;
  if (rank >= 32) return;   // cannot happen at 1 blk/CU; safety

  // ---- W_hh fragments -> registers (step-invariant) ----
  // local gate row n = cl*4+g  (cl = local col 0..31, g = gate)
  f16x8 Bf[8][4];
#pragma unroll
  for (int nt = 0; nt < 8; ++nt) {
    int n = nt * 16 + lc;
    const f16* wrow = Whh + ((long)(n & 3) * 1024 + rank * 32 + (n >> 2)) * 1024;
#pragma unroll
    for (int kt = 0; kt < 4; ++kt)
      Bf[nt][kt] = *(const f16x8*)(wrow + w * 128 + kt * 32 + lr * 8);
  }

  // ---- cell-phase ownership (tid<128): (b_local, c_own) ----
  const int b_local = tid >> 5;            // 0..3 (tid<128)
  const int bglob = xcd * 4 + (b_local & 3);
  const int c_own = tid & 31;
  const int j_own = rank * 32 + c_own;
  float c_reg = 0.f; float4 pg4 = {0,0,0,0}; float4 nt4 = {0,0,0,0};
  if (tid < 128) {
    c_reg = c0[(long)bglob * 1024 + j_own];
    pg4 = *(const float4*)(prod_gates + (long)bglob * 4096 + j_own * 4);
    int nid0 = nt_ids[bglob];
    nt4 = *(const float4*)(nt_table + (long)nid0 * 4096 + j_own * 4);
  }

  // consumer A base: batch (lc&3) of this XCD, K-chunk of wave w
  const f16* pA = st + ((long)xcd * 4 + (lc & 3)) * 1024 + w * 128 + lr * 8;
  int esc = 0;   // escalation counter

#define KA8(a,b,c,d,e,f,g,h) asm volatile("" : "+v"(a),"+v"(b),"+v"(c),"+v"(d),\
                                               "+v"(e),"+v"(f),"+v"(g),"+v"(h))

  for (int t = 0; t < TT; ++t) {
    // pin W_hh fragments live across the loop (defeat load re-sinking)
    KA8(Bf[0][0],Bf[0][1],Bf[0][2],Bf[0][3],Bf[1][0],Bf[1][1],Bf[1][2],Bf[1][3]);
    KA8(Bf[2][0],Bf[2][1],Bf[2][2],Bf[2][3],Bf[3][0],Bf[3][1],Bf[3][2],Bf[3][3]);
    KA8(Bf[4][0],Bf[4][1],Bf[4][2],Bf[4][3],Bf[5][0],Bf[5][1],Bf[5][2],Bf[5][3]);
    KA8(Bf[6][0],Bf[6][1],Bf[6][2],Bf[6][3],Bf[7][0],Bf[7][1],Bf[7][2],Bf[7][3]);

    // ---- poison-poll A directly (sc0: L1-bypass, served by XCD L2) ----
    u32x4 Ar[4];
    {
      const f16* pt = pA + (long)t * 32768;
      while (true) {
        if (esc < 4096) {
          asm volatile(
            "global_load_dwordx4 %0, %4, off sc0\n\t"
            "global_load_dwordx4 %1, %4, off offset:64 sc0\n\t"
            "global_load_dwordx4 %2, %4, off offset:128 sc0\n\t"
            "global_load_dwordx4 %3, %4, off offset:192 sc0\n\t"
            "s_waitcnt vmcnt(0)"
            : "=&v"(Ar[0]), "=&v"(Ar[1]), "=&v"(Ar[2]), "=&v"(Ar[3])
            : "v"(pt) : "memory");
        } else {   // escalation: device scope (bounds worst case, no hang)
          asm volatile(
            "global_load_dwordx4 %0, %4, off sc0 sc1\n\t"
            "global_load_dwordx4 %1, %4, off offset:64 sc0 sc1\n\t"
            "global_load_dwordx4 %2, %4, off offset:128 sc0 sc1\n\t"
            "global_load_dwordx4 %3, %4, off offset:192 sc0 sc1\n\t"
            "s_waitcnt vmcnt(0)"
            : "=&v"(Ar[0]), "=&v"(Ar[1]), "=&v"(Ar[2]), "=&v"(Ar[3])
            : "v"(pt) : "memory");
        }
        unsigned mA = 0, mB = 0, mC = 0, mD = 0;
#pragma unroll
        for (int kt = 0; kt < 4; ++kt) {
          asm("v_pk_max_u16 %0, %0, %1" : "+v"(mA) : "v"(Ar[kt].x));
          asm("v_pk_max_u16 %0, %0, %1" : "+v"(mB) : "v"(Ar[kt].y));
          asm("v_pk_max_u16 %0, %0, %1" : "+v"(mC) : "v"(Ar[kt].z));
          asm("v_pk_max_u16 %0, %0, %1" : "+v"(mD) : "v"(Ar[kt].w));
        }
        asm("v_pk_max_u16 %0, %0, %1" : "+v"(mA) : "v"(mB));
        asm("v_pk_max_u16 %0, %0, %1" : "+v"(mC) : "v"(mD));
        asm("v_pk_max_u16 %0, %0, %1" : "+v"(mA) : "v"(mC));
        int ok = !(((mA & 0xFFFFu) == 0xFFFFu) || ((mA >> 16) == 0xFFFFu));
        if (__all(ok)) break;
        ++esc;
        __builtin_amdgcn_s_sleep(1);
      }
      __builtin_amdgcn_sched_barrier(0);   // no MFMA hoist above the waitcnt
    }

    // prefetch next step's nt gates (off the critical path)
    float4 nt4n = nt4;
    if (tid < 128 && t + 1 < TT) {
      int nidn = nt_ids[(t + 1) * 32 + bglob];
      nt4n = *(const float4*)(nt_table + (long)nidn * 4096 + j_own * 4);
    }

    // ---- MFMA: 1 M-tile (4 real batches) x 8 N-tiles x 4 kt ----
    f32x4 acc[8];
#pragma unroll
    for (int nt = 0; nt < 8; ++nt) { f32x4 zz = {0.f,0.f,0.f,0.f}; acc[nt] = zz; }
#pragma unroll
    for (int kt = 0; kt < 4; ++kt) {
      f16x8 av = __builtin_bit_cast(f16x8, Ar[kt]);
#pragma unroll
      for (int nt = 0; nt < 8; ++nt)
        acc[nt] = __builtin_amdgcn_mfma_f32_16x16x32_f16(av, Bf[nt][kt], acc[nt], 0, 0, 0);
    }
    // only C rows 0-3 are real (lr==0, r = batch)
    float (*pp)[4][32][5] = partial[t & 1];
    if (lr == 0) {
#pragma unroll
      for (int nt = 0; nt < 8; ++nt) {
        int g = lc & 3, cl = nt * 4 + (lc >> 2);
#pragma unroll
        for (int r = 0; r < 4; ++r)
          pp[w][g][cl][r] = acc[nt][r];
      }
    }
    __syncthreads();

    if (tid < 128) {
      // ---- reduce 8 K-slices + LSTM cell ----
      float g4[4] = {0.f, 0.f, 0.f, 0.f};
#pragma unroll
      for (int w8 = 0; w8 < 8; ++w8)
#pragma unroll
        for (int g = 0; g < 4; ++g)
          g4[g] += pp[w8][g][c_own][b_local];

      float ii = sigmoidf_(g4[0] + nt4.x + pg4.x);
      float ff = sigmoidf_(g4[1] + nt4.y + pg4.y);
      float gg = tanhf(g4[2] + nt4.z + pg4.z);
      float oo = sigmoidf_(g4[3] + nt4.w + pg4.w);
      c_reg = ff * c_reg + ii * gg;
      float hn = oo * tanhf(c_reg);
      f16 hi = (f16)hn;
      float lo_f = hn - (float)hi;

      float hn1 = __shfl_down(hn, 1);
      float lo1 = __shfl_down(lo_f, 1);

      // ---- publish h_{t+1}: packed dwords, write-through, fire ----
      if (t + 1 < TT && !(tid & 1)) {
        unsigned pay = pack2h_(hn, hn1);
        f16* pst = st + ((long)(t + 1) * 32 + bglob) * 1024 + j_own;
        asm volatile("global_store_dword %0, %1, off sc0"
                     :: "v"(pst), "v"(pay) : "memory");
      }

      // ---- non-critical stores (consumed post-kernel) ----
      if (!(tid & 1)) {
        long row = (long)bglob * 128 + t;
        *(unsigned*)&q2[row * 2048 + j_own]        = pack2h_(hn, hn1);
        *(unsigned*)&q2[row * 2048 + 1024 + j_own] = pack2h_(lo_f, lo1);
        *(unsigned*)&X[row * 3072 + j_own]         = pack2h_(hn, hn1);
        *(unsigned*)&Y1[row * 2048 + 1024 + j_own] = pack2h_(hn, hn1);
      }
    }
    nt4 = nt4n;
  }
#undef KA8
}

// ---------------------------------------------------------------------------
// Row softmax over 512 cols of sum of 4 fp32 planes -> fp16. One block/row.
__global__ __launch_bounds__(256) void k_softmax4(const float* __restrict__ p,
                                                  long pstride,
                                                  f16* __restrict__ out) {
  long row = blockIdx.x;
  const float* p0 = p + row * 512;
  out += row * 512;
  const int tid = threadIdx.x, w = tid >> 6, lane = tid & 63;
  float vx = 0.f, vy = 0.f;
#pragma unroll
  for (int s = 0; s < 4; ++s) {
    float2 a = ((const float2*)(p0 + s * pstride))[tid];
    vx += a.x; vy += a.y;
  }
  float m = fmaxf(vx, vy);
#pragma unroll
  for (int off = 32; off; off >>= 1) m = fmaxf(m, __shfl_xor(m, off));
  __shared__ float red[8];
  if (lane == 0) red[w] = m;
  __syncthreads();
  m = fmaxf(fmaxf(red[0], red[1]), fmaxf(red[2], red[3]));
  float e0 = __expf(vx - m), e1 = __expf(vy - m);
  float s2 = e0 + e1;
#pragma unroll
  for (int off = 32; off; off >>= 1) s2 += __shfl_xor(s2, off);
  if (lane == 0) red[4 + w] = s2;
  __syncthreads();
  s2 = red[4] + red[5] + red[6] + red[7];
  float inv = 1.0f / s2;
  out[tid * 2]     = (f16)(e0 * inv);
  out[tid * 2 + 1] = (f16)(e1 * inv);
}

// ---------------------------------------------------------------------------
extern "C" void kernel_launch(void* const* d_in, const int* in_sizes, int n_in,
                              void* d_out, int out_size, void* d_ws, size_t ws_size,
                              hipStream_t stream)
{
  const int*   init_prod = (const int*)d_in[0];
  const int*   nt_ids    = (const int*)d_in[1];
  const float* h0   = (const float*)d_in[2];
  const float* c0   = (const float*)d_in[3];
  const float* nl   = (const float*)d_in[4];
  const float* env  = (const float*)d_in[5];
  const float* nt_emb   = (const float*)d_in[6];
  const float* rule_emb = (const float*)d_in[7];
  const float* W_ih = (const float*)d_in[8];
  const float* W_hh = (const float*)d_in[9];
  const float* b_ih = (const float*)d_in[10];
  const float* b_hh = (const float*)d_in[11];
  const float* Wz   = (const float*)d_in[12];
  const float* bz   = (const float*)d_in[13];
  const float* We   = (const float*)d_in[14];
  const float* be   = (const float*)d_in[15];
  const float* Wc   = (const float*)d_in[16];
  const float* bc   = (const float*)d_in[17];
  float* out = (float*)d_out;
  (void)in_sizes; (void)n_in; (void)out_size; (void)ws_size;

  size_t off = 0;
  auto carve = [&](size_t bytes) {
    char* p = (char*)d_ws + off;
    off += (bytes + 255) & ~(size_t)255;
    return (void*)p;
  };
  f16*   Whh_h   = (f16*)carve(4096L * 1024 * 2);
  f16*   Wz_h    = (f16*)carve(1024L * 2048 * 2);
  f16*   We_h    = (f16*)carve(1024L * 2048 * 2);
  f16*   Wc_h    = (f16*)carve(1024L * 3072 * 2);
  f16*   nte_h   = (f16*)carve(200L * 1024 * 2);
  f16*   prod_h  = (f16*)carve(32L * 1024 * 2);
  float* nt_table   = (float*)carve(200L * 4096 * 4);   // gate-interleaved
  float* prod_gates = (float*)carve(32L * 4096 * 4);    // gate-interleaved
  f16*   st_hi   = (f16*)carve(129L * 32 * 1024 * 2);   // [t][b][j]
  f16*   q2      = (f16*)carve(4096L * 2048 * 2);   // query hi|lo (h, then zt)
  f16*   X       = (f16*)carve(4096L * 3072 * 2);   // [h | zt | et] for ct GEMM
  f16*   Y1      = (f16*)carve(4096L * 2048 * 2);   // [mix1 | h]  for zt GEMM
  f16*   Y2      = (f16*)carve(4096L * 2048 * 2);   // [mix2 | zt] for et GEMM
  f16*   ctx_h   = (f16*)carve(32L * 512 * 1024 * 2);
  f16*   ctxT    = (f16*)carve(32L * 1024 * 512 * 2);
  float* scoresP = (float*)carve(4L * 32 * 128 * 512 * 4);  // 4 split-K planes
  f16*   attn    = (f16*)carve(4096L * 512 * 2);
  int*   bar     = (int*)carve(256);   // 8 per-XCD rank counters
  f16*   Wih_h   = (f16*)X;   // alias: Wih dead before LSTM writes X

  auto f2h = [&](const float* src, f16* dst, long n) {
    long n4 = n / 4;
    k_f2h<<<dim3((unsigned)((n4 + 255) / 256)), dim3(256), 0, stream>>>(src, dst, n4);
  };
  f2h(W_ih, Wih_h, 4096L * 2048);
  f2h(W_hh, Whh_h, 4096L * 1024);
  f2h(Wz,   Wz_h,  1024L * 2048);
  f2h(We,   We_h,  1024L * 2048);
  f2h(Wc,   Wc_h,  1024L * 3072);
  f2h(nt_emb, nte_h, 200L * 1024);
  k_gather_prod<<<dim3(128), dim3(256), 0, stream>>>(rule_emb, init_prod, prod_h);
  // poison h slots 1..128, write h0 into slot 0, zero rank counters
  k_poison<<<dim3(8192), dim3(256), 0, stream>>>(
      (unsigned int*)st_hi + 16384, 128L * 16384);
  k_h0<<<dim3(128), dim3(256), 0, stream>>>(h0, st_hi);
  k_zero<<<dim3(1), dim3(256), 0, stream>>>(bar, 64);

  auto gemm = [&](const f16* A, long lda, long sA,
                  const f16* B, long ldb, long sB,
                  float* oF, long ldF, long sF, long sSl,
                  f16* oH, long ldH, long sH,
                  f16* oH2, long ldH2, long sH2,
                  f16* o2, long ld2, long s2,
                  const float* b1, const float* b2,
                  int M, int N, int K, int act, int bmod, int zdiv, int ilv,
                  int batch) {
    dim3 grid((unsigned)((M + 127) / 128), (unsigned)((N + 127) / 128),
              (unsigned)(batch * zdiv));
    k_gemm<<<grid, dim3(256), 0, stream>>>(A, lda, sA, B, ldb, sB,
                                           oF, ldF, sF, sSl, oH, ldH, sH,
                                           oH2, ldH2, sH2, o2, ld2, s2,
                                           b1, b2, M, N, K, act, bmod, zdiv, ilv);
  };
  const long SPL = 32L * 128 * 512;   // split-K plane stride (floats)

  // gate tables (gate-interleaved fp32 layout via ilv=1)
  gemm(nte_h, 1024, 0, Wih_h, 2048, 0, nt_table, 4096, 0, 0,
       nullptr,0,0, nullptr,0,0, nullptr,0,0, nullptr, nullptr,
       200, 4096, 1024, 0, 0, 1, 1, 1);
  gemm(prod_h, 1024, 0, Wih_h + 1024, 2048, 0, prod_gates, 4096, 0, 0,
       nullptr,0,0, nullptr,0,0, nullptr,0,0, b_ih, b_hh,
       32, 4096, 1024, 0, 0, 1, 1, 1);

  // persistent LSTM: 256 blocks (1/CU), XCD-local dataflow
  k_lstm_all<<<dim3(256), dim3(512), 0, stream>>>(
      Whh_h, nt_table, prod_gates, nt_ids, c0, st_hi, q2, X, Y1, bar);

  // --- attention over nl ---
  k_transpose<<<dim3(16, 32, 32), dim3(256), 0, stream>>>(nl, ctxT, ctx_h);
  gemm(q2, 2048, 128L * 2048, ctx_h, 1024, 512L * 1024,
       scoresP, 512, 128L * 512, SPL, nullptr,0,0, nullptr,0,0, nullptr,0,0,
       nullptr, nullptr, 128, 512, 2048, 0, 1024, 4, 0, 32);
  k_softmax4<<<dim3(4096), dim3(256), 0, stream>>>(scoresP, SPL, attn);
  gemm(attn, 512, 128L * 512, ctxT, 512, 1024L * 512,
       nullptr,0,0,0, Y1, 2048, 128L * 2048, nullptr,0,0, nullptr,0,0,
       nullptr, nullptr, 128, 1024, 512, 0, 0, 1, 0, 32);
  // zt = tanh(Y1=[mix1|h] @ Wz^T + bz) -> X[:,1024:2048), Y2[:,1024:2048), q2
  gemm(Y1, 2048, 0, Wz_h, 2048, 0,
       nullptr,0,0,0, X + 1024, 3072, 0, Y2 + 1024, 2048, 0, q2, 2048, 0,
       bz, nullptr, 4096, 1024, 2048, 1, 0, 1, 0, 1);

  // --- attention over env ---
  k_transpose<<<dim3(16, 32, 32), dim3(256), 0, stream>>>(env, ctxT, ctx_h);
  gemm(q2, 2048, 128L * 2048, ctx_h, 1024, 512L * 1024,
       scoresP, 512, 128L * 512, SPL, nullptr,0,0, nullptr,0,0, nullptr,0,0,
       nullptr, nullptr, 128, 512, 2048, 0, 1024, 4, 0, 32);
  k_softmax4<<<dim3(4096), dim3(256), 0, stream>>>(scoresP, SPL, attn);
  gemm(attn, 512, 128L * 512, ctxT, 512, 1024L * 512,
       nullptr,0,0,0, Y2, 2048, 128L * 2048, nullptr,0,0, nullptr,0,0,
       nullptr, nullptr, 128, 1024, 512, 0, 0, 1, 0, 32);
  // et = tanh(Y2=[mix2|zt] @ We^T + be) -> X[:,2048:3072)
  gemm(Y2, 2048, 0, We_h, 2048, 0,
       nullptr,0,0,0, X + 2048, 3072, 0, nullptr,0,0, nullptr,0,0,
       be, nullptr, 4096, 1024, 2048, 1, 0, 1, 0, 1);

  // --- ct = tanh(X=[h|zt|et] @ Wc^T + bc) -> d_out (T,B,H) ---
  gemm(X, 3072, 128L * 3072, Wc_h, 3072, 0,
       out, 32L * 1024, 1024, 0, nullptr,0,0, nullptr,0,0, nullptr,0,0,
       bc, nullptr, 128, 1024, 3072, 1, 0, 1, 0, 32);
}

// Round 8
// 1270.121 us; speedup vs baseline: 5.1857x; 5.1857x over previous
//
#include <hip/hip_runtime.h>
#include <hip/hip_bf16.h>

typedef _Float16 f16;
typedef __attribute__((ext_vector_type(8))) _Float16 f16x8;
typedef __attribute__((ext_vector_type(4))) float f32x4;
typedef __attribute__((ext_vector_type(4))) unsigned int u32x4;
typedef __attribute__((ext_vector_type(2))) int i32x2;

#define TT 128

__device__ __forceinline__ float sigmoidf_(float x) { return 1.0f / (1.0f + __expf(-x)); }

// ---------------------------------------------------------------------------
// Fused prep: all fp32->fp16 weight converts + rule_emb gather + h0 seed +
// flag zeroing in ONE launch (replaces 9 tiny kernels; saves launch gaps).
__global__ __launch_bounds__(256) void k_prep(
    const float* __restrict__ W_ih, const float* __restrict__ W_hh,
    const float* __restrict__ Wz, const float* __restrict__ We,
    const float* __restrict__ Wc, const float* __restrict__ nt_emb,
    const float* __restrict__ rule_emb, const int* __restrict__ init_prod,
    const float* __restrict__ h0,
    f16* __restrict__ Wih_h, f16* __restrict__ Whh_h,
    f16* __restrict__ Wz_h, f16* __restrict__ We_h, f16* __restrict__ Wc_h,
    f16* __restrict__ nte_h, f16* __restrict__ prod_h,
    f16* __restrict__ st, int* __restrict__ bar)
{
  const long nWih = 2097152, nWhh = 1048576, nWz = 524288, nWe = 524288,
             nWc = 786432, nNte = 51200, nGat = 32768, nH0 = 32768, nZ = 512;
  const long T0 = nWih, T1 = T0 + nWhh, T2 = T1 + nWz, T3 = T2 + nWe,
             T4 = T3 + nWc, T5 = T4 + nNte, T6 = T5 + nGat, T7 = T6 + nH0,
             T8 = T7 + nZ;
  const long stride = (long)gridDim.x * 256;
  for (long i = (long)blockIdx.x * 256 + threadIdx.x; i < T8; i += stride) {
    if (i < T5) {              // float4 -> 4x f16 converts
      const float* src; f16* dst; long j;
      if (i < T0)      { src = W_ih;   dst = Wih_h; j = i; }
      else if (i < T1) { src = W_hh;   dst = Whh_h; j = i - T0; }
      else if (i < T2) { src = Wz;     dst = Wz_h;  j = i - T1; }
      else if (i < T3) { src = We;     dst = We_h;  j = i - T2; }
      else if (i < T4) { src = Wc;     dst = Wc_h;  j = i - T3; }
      else             { src = nt_emb; dst = nte_h; j = i - T4; }
      float4 v = ((const float4*)src)[j];
      dst[j*4+0] = (f16)v.x; dst[j*4+1] = (f16)v.y;
      dst[j*4+2] = (f16)v.z; dst[j*4+3] = (f16)v.w;
    } else if (i < T6) {       // gather rule_emb rows for init_prod
      long j = i - T5; int b = (int)(j >> 10), k = (int)(j & 1023);
      prod_h[j] = (f16)rule_emb[(long)init_prod[b] * 1024 + k];
    } else if (i < T7) {       // h0 -> st slot 0 ([t][bx][b][jj] layout)
      long j = i - T6; int b = (int)(j >> 10), k = (int)(j & 1023);
      st[(long)(k >> 3) * 256 + b * 8 + (k & 7)] = (f16)h0[j];
    } else {                   // zero flags
      bar[i - T7] = 0;
    }
  }
}

// ---------------------------------------------------------------------------
// fp16 MFMA GEMM: C[M,N] = act( A[M,K] @ B[N,K]^T + bias1 + bias2 )
// 128x128 tile, BK=32, register-prefetch double buffer.
// bmod: B K-index wraps mod bmod. zdiv: split-K, partials at outF+slice*sSl.
// ilv: outF column remap col -> (col&1023)*4 + (col>>10)  (gate-interleave).
// bf32: B operand is fp32 in memory (read float4 pairs, convert to f16 in
//   staging) -- lets score GEMMs consume nl/env DIRECTLY, deleting the 64MB
//   of f16 ctxN copies that blew the ~216MB workspace envelope in R7.
__global__ __launch_bounds__(256) void k_gemm(
    const f16* __restrict__ A, long lda, long sA,
    const f16* __restrict__ B, long ldb, long sB,
    float* __restrict__ outF, long ldF, long sF, long sSl,
    f16* __restrict__ outH, long ldH, long sH,
    f16* __restrict__ outH2, long ldH2, long sH2,
    f16* __restrict__ out2, long ld2, long s2,
    const float* __restrict__ bias1, const float* __restrict__ bias2,
    int M, int N, int K, int act, int bmod, int zdiv, int ilv, int bf32)
{
  __shared__ __align__(16) f16 As[128][40];
  __shared__ __align__(16) f16 Bs[128][40];
  const int tid = threadIdx.x;
  const int w = tid >> 6, lane = tid & 63;
  const int wm = (w & 1) * 64, wn = (w >> 1) * 64;
  const int lr = lane >> 4, lc = lane & 15;
  const long m0 = (long)blockIdx.x * 128;
  const long n0 = (long)blockIdx.y * 128;
  int z = blockIdx.z, batch = z, slice = 0, Ks = K;
  if (zdiv > 1) { batch = z / zdiv; slice = z - batch * zdiv; Ks = K / zdiv; }
  const long kbeg = (long)slice * Ks;
  A += (long)batch * sA;
  const float* B32 = nullptr;
  if (bf32) B32 = (const float*)B + (long)batch * sB;
  else      B += (long)batch * sB;

  const int rr = tid >> 2, sg = (tid & 3) * 8;
  const int nIt = Ks / 32;

  auto loadB = [&](int row, long kb) -> uint4 {
    uint4 vb = {0,0,0,0};
    if (n0 + row < N) {
      if (bf32) {
        const float* p = B32 + (n0 + row) * ldb + kb + sg;
        float4 v0 = *(const float4*)p;
        float4 v1 = *(const float4*)(p + 4);
        union { f16 h[8]; uint4 u; } cv;
        cv.h[0] = (f16)v0.x; cv.h[1] = (f16)v0.y;
        cv.h[2] = (f16)v0.z; cv.h[3] = (f16)v0.w;
        cv.h[4] = (f16)v1.x; cv.h[5] = (f16)v1.y;
        cv.h[6] = (f16)v1.z; cv.h[7] = (f16)v1.w;
        vb = cv.u;
      } else {
        vb = *(const uint4*)(B + (n0 + row) * ldb + kb + sg);
      }
    }
    return vb;
  };

  uint4 pa[2], pb[2];
  {
    long k = kbeg;
    long kb = bmod ? (k & (bmod - 1)) : k;
#pragma unroll
    for (int p = 0; p < 2; ++p) {
      int row = p * 64 + rr;
      uint4 va = {0,0,0,0};
      if (m0 + row < M) va = *(const uint4*)(A + (m0 + row) * lda + k + sg);
      pa[p] = va; pb[p] = loadB(row, kb);
    }
  }

  f32x4 acc[4][4];
#pragma unroll
  for (int i = 0; i < 4; ++i)
#pragma unroll
    for (int j = 0; j < 4; ++j) { f32x4 zz = {0.f,0.f,0.f,0.f}; acc[i][j] = zz; }

  for (int it = 0; it < nIt; ++it) {
#pragma unroll
    for (int p = 0; p < 2; ++p) {
      *(uint4*)&As[p * 64 + rr][sg] = pa[p];
      *(uint4*)&Bs[p * 64 + rr][sg] = pb[p];
    }
    __syncthreads();
    if (it + 1 < nIt) {
      long k = kbeg + (long)(it + 1) * 32;
      long kb = bmod ? (k & (bmod - 1)) : k;
#pragma unroll
      for (int p = 0; p < 2; ++p) {
        int row = p * 64 + rr;
        uint4 va = {0,0,0,0};
        if (m0 + row < M) va = *(const uint4*)(A + (m0 + row) * lda + k + sg);
        pa[p] = va; pb[p] = loadB(row, kb);
      }
    }
    f16x8 af[4], bf[4];
#pragma unroll
    for (int i = 0; i < 4; ++i) af[i] = *(const f16x8*)&As[wm + i*16 + lc][lr * 8];
#pragma unroll
    for (int j = 0; j < 4; ++j) bf[j] = *(const f16x8*)&Bs[wn + j*16 + lc][lr * 8];
#pragma unroll
    for (int i = 0; i < 4; ++i)
#pragma unroll
      for (int j = 0; j < 4; ++j)
        acc[i][j] = __builtin_amdgcn_mfma_f32_16x16x32_f16(af[i], bf[j], acc[i][j], 0, 0, 0);
    __syncthreads();
  }

  if (outF)  outF  += (long)batch * sF + (long)slice * sSl;
  if (outH)  outH  += (long)batch * sH;
  if (outH2) outH2 += (long)batch * sH2;
  if (out2)  out2  += (long)batch * s2;
#pragma unroll
  for (int i = 0; i < 4; ++i)
#pragma unroll
    for (int j = 0; j < 4; ++j)
#pragma unroll
      for (int r = 0; r < 4; ++r) {
        long row = m0 + wm + i * 16 + lr * 4 + r;
        long col = n0 + wn + j * 16 + lc;
        if (row < M && col < N) {
          float v = acc[i][j][r];
          if (bias1) v += bias1[col];
          if (bias2) v += bias2[col];
          if (act)   v = tanhf(v);
          if (outF) {
            long fc = ilv ? ((col & 1023) * 4 + (col >> 10)) : col;
            outF[row * ldF + fc] = v;
          }
          if (outH)  outH[row * ldH + col] = (f16)v;
          if (outH2) outH2[row * ldH2 + col] = (f16)v;
          if (out2) {
            f16 hi = (f16)v;
            out2[row * ld2 + col]        = hi;
            out2[row * ld2 + 1024 + col] = (f16)(v - (float)hi);
          }
        }
      }
}

// ---------------------------------------------------------------------------
// Persistent LSTM (R3-proven flag-gated dataflow) + FUSED context transposes.
// 256 blocks x 256 threads, 1 block/CU (105KB LDS):
//   blocks 0..127:  the R3 LSTM (verified at 495us). Block bx owns 8
//     h-columns x 4 gates x 32 batches; W_hh fragments in registers;
//     h exchange: packed dwordx4 sc0 sc1 stores -> vmcnt ack -> wave flag;
//     consumers poll 128 producer flags (dwordx2/lane) then one A-burst.
//   blocks 128..255: transpose nl and env (B,512,1024)fp32 -> (B,H,L)f16
//     (ctxT only -- score GEMMs read fp32 ctx directly via bf32) on the
//     OTHERWISE-IDLE half of the chip, hidden under the LSTM's ~500us
//     latency-bound shadow.
__global__ __launch_bounds__(256) void k_lstm_all(
    const f16* __restrict__ Whh,          // (4096,1024)
    const float* __restrict__ nt_table,   // (200,1024,4) gate-interleaved
    const float* __restrict__ prod_gates, // (32,1024,4) gate-interleaved
    const int* __restrict__ nt_ids,       // (128,32)
    const float* __restrict__ c0,         // (32,1024)
    f16* __restrict__ st,                 // (129,128,32,8) step/block-major
    f16* __restrict__ q2,                 // (4096,2048) hi|lo
    f16* __restrict__ X,                  // (4096,3072)
    f16* __restrict__ Y1,                 // (4096,2048)
    int* __restrict__ flags,              // 512 dense ints: [bx][wave]
    const float* __restrict__ nl,         // (32,512,1024) fp32
    const float* __restrict__ env,        // (32,512,1024) fp32
    f16* __restrict__ ctxT_nl, f16* __restrict__ ctxT_env)
{
  __shared__ __align__(16) f16 whh_s[32][1032];
  __shared__ float partial[2][4][32][34];
  __shared__ float tile[32][33];
  const int tid = threadIdx.x;
  const int bx = blockIdx.x;

  if (bx >= 128) {
    // ---------------- transpose worker ----------------
    const int me = bx - 128;
    const int c = tid & 31, r = tid >> 5;
#pragma unroll
    for (int pass = 0; pass < 2; ++pass) {
      const float* in = pass ? env : nl;
      f16* oT = pass ? ctxT_env : ctxT_nl;
      for (int idx = me; idx < 16384; idx += 128) {
        int b = idx >> 9, rr2 = idx & 511;
        int l0 = (rr2 & 15) * 32, h0v = (rr2 >> 4) * 32;
        const float* inb = in + (long)b * 512 * 1024;
        f16* oTb = oT + (long)b * 1024 * 512;
#pragma unroll
        for (int p = 0; p < 4; ++p)
          tile[r + p*8][c] = inb[(long)(l0 + r + p*8) * 1024 + h0v + c];
        __syncthreads();
#pragma unroll
        for (int p = 0; p < 4; ++p)
          oTb[(long)(h0v + r + p*8) * 512 + l0 + c] = (f16)tile[c][r + p*8];
        __syncthreads();   // tile reused next iteration
      }
    }
    return;
  }

  // ---------------- LSTM (identical to R3) ----------------
  const int w = tid >> 6, lane = tid & 63;
  const int lr = lane >> 4, lc = lane & 15;
  const int j0 = bx * 8;

  // stage Whh slice: LDS row r=(g*8+jj) <- global row g*1024 + j0 + jj
  for (int i = tid; i < 32 * 128; i += 256) {
    int r = i >> 7, c8 = i & 127;
    int g = r >> 3, jj = r & 7;
    *(uint4*)&whh_s[r][c8 * 8] =
        *(const uint4*)(Whh + ((long)g * 1024 + j0 + jj) * 1024 + c8 * 8);
  }
  const int b_own = tid >> 3, jj_own = tid & 7;
  const int j_own = j0 + jj_own;
  float c_reg = c0[(long)b_own * 1024 + j_own];
  float4 pg4 = *(const float4*)(prod_gates + (long)b_own * 4096 + j_own * 4);
  int nid0 = nt_ids[b_own];
  float4 nt4 = *(const float4*)(nt_table + (long)nid0 * 4096 + j_own * 4);
  __syncthreads();   // whh_s ready

  // hoist step-invariant B fragments LDS -> registers (whh_s dead afterwards)
  f16x8 B0[8], B1[8];
#pragma unroll
  for (int kt = 0; kt < 8; ++kt) {
    int k = w * 256 + kt * 32 + lr * 8;
    B0[kt] = *(const f16x8*)&whh_s[lc][k];
    B1[kt] = *(const f16x8*)&whh_s[16 + lc][k];
  }

  // A base: fragment kt of wave w = st[t][w*32+kt*4+lr][lc or 16+lc][0..8)
  const f16* pA = st + (long)(w * 32 + lr) * 256 + lc * 8;
  const int* fp = flags + w * 128 + lane * 2;   // this wave's 128 producer flags

  for (int t = 0; t < TT; ++t) {
    // ---- poll producer flags (tiny, coalesced) ----
    if (t > 0) {
      int done = 0;
      while (true) {
        if (!done) {
          i32x2 ff;
          asm volatile("global_load_dwordx2 %0, %1, off sc0 sc1\n\t"
                       "s_waitcnt vmcnt(0)"
                       : "=&v"(ff) : "v"(fp) : "memory");
          done = (ff.x >= t) & (ff.y >= t);
        }
        if (__all(done)) break;
        __builtin_amdgcn_s_sleep(1);
      }
    }

    // ---- single A-burst: 16 x dwordx4 sc0 sc1 ----
    u32x4 A0[8], A1[8];
    {
      const f16* pt = pA + (long)t * 32768;
#pragma unroll
      for (int q = 0; q < 4; ++q) {
        asm volatile(
          "global_load_dwordx4 %0, %4, off sc0 sc1\n\t"
          "global_load_dwordx4 %1, %4, off offset:256 sc0 sc1\n\t"
          "global_load_dwordx4 %2, %4, off offset:2048 sc0 sc1\n\t"
          "global_load_dwordx4 %3, %4, off offset:2304 sc0 sc1"
          : "=&v"(A0[2*q]), "=&v"(A1[2*q]), "=&v"(A0[2*q+1]), "=&v"(A1[2*q+1])
          : "v"(pt + (long)q * 2048) : "memory");
      }
      asm volatile("s_waitcnt vmcnt(0)" ::: "memory");
      __builtin_amdgcn_sched_barrier(0);   // no MFMA hoist above the waitcnt
    }

    // prefetch next step's nt gates (off the critical path)
    float4 nt4n = nt4;
    if (t + 1 < TT) {
      int nidn = nt_ids[(t + 1) * 32 + b_own];
      nt4n = *(const float4*)(nt_table + (long)nidn * 4096 + j_own * 4);
    }

    f32x4 acc[2][2];
#pragma unroll
    for (int i = 0; i < 2; ++i)
#pragma unroll
      for (int j = 0; j < 2; ++j) { f32x4 zz = {0.f,0.f,0.f,0.f}; acc[i][j] = zz; }
#pragma unroll
    for (int kt = 0; kt < 8; ++kt) {
      f16x8 a0v = __builtin_bit_cast(f16x8, A0[kt]);
      f16x8 a1v = __builtin_bit_cast(f16x8, A1[kt]);
      acc[0][0] = __builtin_amdgcn_mfma_f32_16x16x32_f16(a0v, B0[kt], acc[0][0], 0, 0, 0);
      acc[0][1] = __builtin_amdgcn_mfma_f32_16x16x32_f16(a0v, B1[kt], acc[0][1], 0, 0, 0);
      acc[1][0] = __builtin_amdgcn_mfma_f32_16x16x32_f16(a1v, B0[kt], acc[1][0], 0, 0, 0);
      acc[1][1] = __builtin_amdgcn_mfma_f32_16x16x32_f16(a1v, B1[kt], acc[1][1], 0, 0, 0);
    }
    float (*pp)[32][34] = partial[t & 1];
#pragma unroll
    for (int mi = 0; mi < 2; ++mi)
#pragma unroll
      for (int ni = 0; ni < 2; ++ni)
#pragma unroll
        for (int r = 0; r < 4; ++r)
          pp[w][ni * 16 + lc][mi * 16 + lr * 4 + r] = acc[mi][ni][r];
    __syncthreads();

    // reduce 4 K-slices + LSTM cell (double-buffered partial: no 2nd barrier)
    float g4[4];
#pragma unroll
    for (int g = 0; g < 4; ++g) {
      int rrow = g * 8 + jj_own;
      g4[g] = pp[0][rrow][b_own] + pp[1][rrow][b_own] +
              pp[2][rrow][b_own] + pp[3][rrow][b_own];
    }
    float ii = sigmoidf_(g4[0] + nt4.x + pg4.x);
    float ff = sigmoidf_(g4[1] + nt4.y + pg4.y);
    float gg = tanhf(g4[2] + nt4.z + pg4.z);
    float oo = sigmoidf_(g4[3] + nt4.w + pg4.w);
    c_reg = ff * c_reg + ii * gg;
    float hn = oo * tanhf(c_reg);
    f16 hi = (f16)hn;

    // ---- publish h_{t+1}: pack 8 halves -> one dwordx4 per group ----
    if (t + 1 < TT) {
      union { f16 h; unsigned short u; } cv; cv.h = hi;
      unsigned me2 = cv.u;
      unsigned d  = me2 | ((unsigned)__shfl_down((int)me2, 1) << 16);
      unsigned d2 = (unsigned)__shfl_down((int)d, 2);
      unsigned e0 = (unsigned)__shfl_down((int)d, 4);
      unsigned e1 = (unsigned)__shfl_down((int)d2, 4);
      if (jj_own == 0) {
        u32x4 pay; pay.x = d; pay.y = d2; pay.z = e0; pay.w = e1;
        f16* pst = st + (long)(t + 1) * 32768 + bx * 256 + b_own * 8;
        asm volatile("global_store_dwordx4 %0, %1, off sc0 sc1"
                     :: "v"(pst), "v"(pay) : "memory");
      }
      asm volatile("s_waitcnt vmcnt(0)" ::: "memory");   // data acked
      if (lane == 0) {
        int* myf = flags + bx * 4 + w;
        int fv = t + 1;
        asm volatile("global_store_dword %0, %1, off sc0 sc1"
                     :: "v"(myf), "v"(fv) : "memory");
      }
    }

    // non-critical stores: complete in the shadow of the next poll
    long row = (long)b_own * 128 + t;
    q2[row * 2048 + j_own]        = hi;
    q2[row * 2048 + 1024 + j_own] = (f16)(hn - (float)hi);
    X[row * 3072 + j_own]         = hi;
    Y1[row * 2048 + 1024 + j_own] = hi;

    nt4 = nt4n;
  }
}

// ---------------------------------------------------------------------------
// Row softmax over 512 cols of sum of 4 fp32 planes -> fp16. One block/row.
__global__ __launch_bounds__(256) void k_softmax4(const float* __restrict__ p,
                                                  long pstride,
                                                  f16* __restrict__ out) {
  long row = blockIdx.x;
  const float* p0 = p + row * 512;
  out += row * 512;
  const int tid = threadIdx.x, w = tid >> 6, lane = tid & 63;
  float vx = 0.f, vy = 0.f;
#pragma unroll
  for (int s = 0; s < 4; ++s) {
    float2 a = ((const float2*)(p0 + s * pstride))[tid];
    vx += a.x; vy += a.y;
  }
  float m = fmaxf(vx, vy);
#pragma unroll
  for (int off = 32; off; off >>= 1) m = fmaxf(m, __shfl_xor(m, off));
  __shared__ float red[8];
  if (lane == 0) red[w] = m;
  __syncthreads();
  m = fmaxf(fmaxf(red[0], red[1]), fmaxf(red[2], red[3]));
  float e0 = __expf(vx - m), e1 = __expf(vy - m);
  float s2 = e0 + e1;
#pragma unroll
  for (int off = 32; off; off >>= 1) s2 += __shfl_xor(s2, off);
  if (lane == 0) red[4 + w] = s2;
  __syncthreads();
  s2 = red[4] + red[5] + red[6] + red[7];
  float inv = 1.0f / s2;
  out[tid * 2]     = (f16)(e0 * inv);
  out[tid * 2 + 1] = (f16)(e1 * inv);
}

// ---------------------------------------------------------------------------
extern "C" void kernel_launch(void* const* d_in, const int* in_sizes, int n_in,
                              void* d_out, int out_size, void* d_ws, size_t ws_size,
                              hipStream_t stream)
{
  const int*   init_prod = (const int*)d_in[0];
  const int*   nt_ids    = (const int*)d_in[1];
  const float* h0   = (const float*)d_in[2];
  const float* c0   = (const float*)d_in[3];
  const float* nl   = (const float*)d_in[4];
  const float* env  = (const float*)d_in[5];
  const float* nt_emb   = (const float*)d_in[6];
  const float* rule_emb = (const float*)d_in[7];
  const float* W_ih = (const float*)d_in[8];
  const float* W_hh = (const float*)d_in[9];
  const float* b_ih = (const float*)d_in[10];
  const float* b_hh = (const float*)d_in[11];
  const float* Wz   = (const float*)d_in[12];
  const float* bz   = (const float*)d_in[13];
  const float* We   = (const float*)d_in[14];
  const float* be   = (const float*)d_in[15];
  const float* Wc   = (const float*)d_in[16];
  const float* bc   = (const float*)d_in[17];
  float* out = (float*)d_out;
  (void)in_sizes; (void)n_in; (void)out_size; (void)ws_size;

  size_t off = 0;
  auto carve = [&](size_t bytes) {
    char* p = (char*)d_ws + off;
    off += (bytes + 255) & ~(size_t)255;
    return (void*)p;
  };
  // Total carve ~216 MB -- matches the R3/R5 proven-safe workspace envelope
  // (R7's 283 MB overflowed and faulted).
  f16*   Whh_h   = (f16*)carve(4096L * 1024 * 2);
  f16*   Wz_h    = (f16*)carve(1024L * 2048 * 2);
  f16*   We_h    = (f16*)carve(1024L * 2048 * 2);
  f16*   Wc_h    = (f16*)carve(1024L * 3072 * 2);
  f16*   nte_h   = (f16*)carve(200L * 1024 * 2);
  f16*   prod_h  = (f16*)carve(32L * 1024 * 2);
  float* nt_table   = (float*)carve(200L * 4096 * 4);   // gate-interleaved
  float* prod_gates = (float*)carve(32L * 4096 * 4);    // gate-interleaved
  f16*   st_hi   = (f16*)carve(129L * 128 * 32 * 8 * 2);  // [t][bx][b][jj]
  f16*   q2      = (f16*)carve(4096L * 2048 * 2);   // query hi|lo (h, then zt)
  f16*   X       = (f16*)carve(4096L * 3072 * 2);   // [h | zt | et] for ct GEMM
  f16*   Y1      = (f16*)carve(4096L * 2048 * 2);   // [mix1 | h]  for zt GEMM
  f16*   Y2      = (f16*)carve(4096L * 2048 * 2);   // [mix2 | zt] for et GEMM
  f16*   ctxT_nl  = (f16*)carve(32L * 1024 * 512 * 2);
  f16*   ctxT_env = (f16*)carve(32L * 1024 * 512 * 2);
  float* scoresP = (float*)carve(4L * 32 * 128 * 512 * 4);  // 4 split-K planes
  f16*   attn    = (f16*)carve(4096L * 512 * 2);
  int*   bar     = (int*)carve(2048);   // 512 dense flags
  f16*   Wih_h   = (f16*)X;   // alias: Wih dead before LSTM writes X

  // fused prep: converts + gather + h0 seed + flag zero (one launch)
  k_prep<<<dim3(8192), dim3(256), 0, stream>>>(
      W_ih, W_hh, Wz, We, Wc, nt_emb, rule_emb, init_prod, h0,
      Wih_h, Whh_h, Wz_h, We_h, Wc_h, nte_h, prod_h, st_hi, bar);

  auto gemm = [&](const f16* A, long lda, long sA,
                  const f16* B, long ldb, long sB,
                  float* oF, long ldF, long sF, long sSl,
                  f16* oH, long ldH, long sH,
                  f16* oH2, long ldH2, long sH2,
                  f16* o2, long ld2, long s2,
                  const float* b1, const float* b2,
                  int M, int N, int K, int act, int bmod, int zdiv, int ilv,
                  int bf32, int batch) {
    dim3 grid((unsigned)((M + 127) / 128), (unsigned)((N + 127) / 128),
              (unsigned)(batch * zdiv));
    k_gemm<<<grid, dim3(256), 0, stream>>>(A, lda, sA, B, ldb, sB,
                                           oF, ldF, sF, sSl, oH, ldH, sH,
                                           oH2, ldH2, sH2, o2, ld2, s2,
                                           b1, b2, M, N, K, act, bmod, zdiv,
                                           ilv, bf32);
  };
  const long SPL = 32L * 128 * 512;   // split-K plane stride (floats)

  // gate tables (gate-interleaved fp32 layout via ilv=1)
  gemm(nte_h, 1024, 0, Wih_h, 2048, 0, nt_table, 4096, 0, 0,
       nullptr,0,0, nullptr,0,0, nullptr,0,0, nullptr, nullptr,
       200, 4096, 1024, 0, 0, 1, 1, 0, 1);
  gemm(prod_h, 1024, 0, Wih_h + 1024, 2048, 0, prod_gates, 4096, 0, 0,
       nullptr,0,0, nullptr,0,0, nullptr,0,0, b_ih, b_hh,
       32, 4096, 1024, 0, 0, 1, 1, 0, 1);

  // persistent LSTM (blocks 0-127) + hidden nl/env transposes (blocks 128-255)
  k_lstm_all<<<dim3(256), dim3(256), 0, stream>>>(
      Whh_h, nt_table, prod_gates, nt_ids, c0, st_hi, q2, X, Y1, bar,
      nl, env, ctxT_nl, ctxT_env);

  // --- attention over nl (score GEMM reads fp32 nl directly via bf32) ---
  gemm(q2, 2048, 128L * 2048, (const f16*)nl, 1024, 512L * 1024,
       scoresP, 512, 128L * 512, SPL, nullptr,0,0, nullptr,0,0, nullptr,0,0,
       nullptr, nullptr, 128, 512, 2048, 0, 1024, 4, 0, 1, 32);
  k_softmax4<<<dim3(4096), dim3(256), 0, stream>>>(scoresP, SPL, attn);
  gemm(attn, 512, 128L * 512, ctxT_nl, 512, 1024L * 512,
       nullptr,0,0,0, Y1, 2048, 128L * 2048, nullptr,0,0, nullptr,0,0,
       nullptr, nullptr, 128, 1024, 512, 0, 0, 1, 0, 0, 32);
  // zt = tanh(Y1=[mix1|h] @ Wz^T + bz) -> X[:,1024:2048), Y2[:,1024:2048), q2
  gemm(Y1, 2048, 0, Wz_h, 2048, 0,
       nullptr,0,0,0, X + 1024, 3072, 0, Y2 + 1024, 2048, 0, q2, 2048, 0,
       bz, nullptr, 4096, 1024, 2048, 1, 0, 1, 0, 0, 1);

  // --- attention over env (score GEMM reads fp32 env directly) ---
  gemm(q2, 2048, 128L * 2048, (const f16*)env, 1024, 512L * 1024,
       scoresP, 512, 128L * 512, SPL, nullptr,0,0, nullptr,0,0, nullptr,0,0,
       nullptr, nullptr, 128, 512, 2048, 0, 1024, 4, 0, 1, 32);
  k_softmax4<<<dim3(4096), dim3(256), 0, stream>>>(scoresP, SPL, attn);
  gemm(attn, 512, 128L * 512, ctxT_env, 512, 1024L * 512,
       nullptr,0,0,0, Y2, 2048, 128L * 2048, nullptr,0,0, nullptr,0,0,
       nullptr, nullptr, 128, 1024, 512, 0, 0, 1, 0, 0, 32);
  // et = tanh(Y2=[mix2|zt] @ We^T + be) -> X[:,2048:3072)
  gemm(Y2, 2048, 0, We_h, 2048, 0,
       nullptr,0,0,0, X + 2048, 3072, 0, nullptr,0,0, nullptr,0,0,
       be, nullptr, 4096, 1024, 2048, 1, 0, 1, 0, 0, 1);

  // --- ct = tanh(X=[h|zt|et] @ Wc^T + bc) -> d_out (T,B,H) ---
  gemm(X, 3072, 128L * 3072, Wc_h, 3072, 0,
       out, 32L * 1024, 1024, 0, nullptr,0,0, nullptr,0,0, nullptr,0,0,
       bc, nullptr, 128, 1024, 3072, 1, 0, 1, 0, 0, 32);
}

// Round 9
// 1099.660 us; speedup vs baseline: 5.9896x; 1.1550x over previous
//
#include <hip/hip_runtime.h>
#include <hip/hip_bf16.h>

typedef _Float16 f16;
typedef __attribute__((ext_vector_type(8))) _Float16 f16x8;
typedef __attribute__((ext_vector_type(4))) float f32x4;
typedef __attribute__((ext_vector_type(4))) unsigned int u32x4;
typedef __attribute__((ext_vector_type(2))) int i32x2;

#define TT 128

__device__ __forceinline__ float sigmoidf_(float x) { return 1.0f / (1.0f + __expf(-x)); }

// ---------------------------------------------------------------------------
// Fused prep: all fp32->fp16 weight converts + rule_emb gather + h0 seed +
// flag zeroing in ONE launch (replaces 9 tiny kernels; saves launch gaps).
__global__ __launch_bounds__(256) void k_prep(
    const float* __restrict__ W_ih, const float* __restrict__ W_hh,
    const float* __restrict__ Wz, const float* __restrict__ We,
    const float* __restrict__ Wc, const float* __restrict__ nt_emb,
    const float* __restrict__ rule_emb, const int* __restrict__ init_prod,
    const float* __restrict__ h0,
    f16* __restrict__ Wih_h, f16* __restrict__ Whh_h,
    f16* __restrict__ Wz_h, f16* __restrict__ We_h, f16* __restrict__ Wc_h,
    f16* __restrict__ nte_h, f16* __restrict__ prod_h,
    f16* __restrict__ st, int* __restrict__ bar)
{
  const long nWih = 2097152, nWhh = 1048576, nWz = 524288, nWe = 524288,
             nWc = 786432, nNte = 51200, nGat = 32768, nH0 = 32768, nZ = 512;
  const long T0 = nWih, T1 = T0 + nWhh, T2 = T1 + nWz, T3 = T2 + nWe,
             T4 = T3 + nWc, T5 = T4 + nNte, T6 = T5 + nGat, T7 = T6 + nH0,
             T8 = T7 + nZ;
  const long stride = (long)gridDim.x * 256;
  for (long i = (long)blockIdx.x * 256 + threadIdx.x; i < T8; i += stride) {
    if (i < T5) {              // float4 -> 4x f16 converts
      const float* src; f16* dst; long j;
      if (i < T0)      { src = W_ih;   dst = Wih_h; j = i; }
      else if (i < T1) { src = W_hh;   dst = Whh_h; j = i - T0; }
      else if (i < T2) { src = Wz;     dst = Wz_h;  j = i - T1; }
      else if (i < T3) { src = We;     dst = We_h;  j = i - T2; }
      else if (i < T4) { src = Wc;     dst = Wc_h;  j = i - T3; }
      else             { src = nt_emb; dst = nte_h; j = i - T4; }
      float4 v = ((const float4*)src)[j];
      dst[j*4+0] = (f16)v.x; dst[j*4+1] = (f16)v.y;
      dst[j*4+2] = (f16)v.z; dst[j*4+3] = (f16)v.w;
    } else if (i < T6) {       // gather rule_emb rows for init_prod
      long j = i - T5; int b = (int)(j >> 10), k = (int)(j & 1023);
      prod_h[j] = (f16)rule_emb[(long)init_prod[b] * 1024 + k];
    } else if (i < T7) {       // h0 -> st slot 0 ([t][bx][b][jj] layout)
      long j = i - T6; int b = (int)(j >> 10), k = (int)(j & 1023);
      st[(long)(k >> 3) * 256 + b * 8 + (k & 7)] = (f16)h0[j];
    } else {                   // zero flags
      bar[i - T7] = 0;
    }
  }
}

// ---------------------------------------------------------------------------
// (B, L=512, H=1024) fp32 -> outT (B, H, L) f16  AND  outN (B, L, H) f16
__global__ __launch_bounds__(256) void k_transpose(const float* __restrict__ in,
                                                   f16* __restrict__ outT,
                                                   f16* __restrict__ outN) {
  __shared__ float tile[32][33];
  const int b  = blockIdx.z;
  const int l0 = blockIdx.x * 32, h0 = blockIdx.y * 32;
  in   += (long)b * 512 * 1024;
  outT += (long)b * 1024 * 512;
  outN += (long)b * 512 * 1024;
  const int c = threadIdx.x & 31, r = threadIdx.x >> 5;
#pragma unroll
  for (int p = 0; p < 4; ++p) {
    float v = in[(long)(l0 + r + p*8) * 1024 + h0 + c];
    tile[r + p*8][c] = v;
    outN[(long)(l0 + r + p*8) * 1024 + h0 + c] = (f16)v;
  }
  __syncthreads();
#pragma unroll
  for (int p = 0; p < 4; ++p)
    outT[(long)(h0 + r + p*8) * 512 + l0 + c] = (f16)tile[c][r + p*8];
}

// ---------------------------------------------------------------------------
// fp16 MFMA GEMM: C[M,N] = act( A[M,K] @ B[N,K]^T + bias1 + bias2 )
// 128x128 tile, BK=32, register-prefetch double buffer.  (R3-proven version,
// bf32 path removed: R8 showed the branchy staging lambda cost ~190us.)
// bmod: B K-index wraps mod bmod. zdiv: split-K, partials at outF+slice*sSl.
// ilv: outF column remap col -> (col&1023)*4 + (col>>10)  (gate-interleave).
__global__ __launch_bounds__(256) void k_gemm(
    const f16* __restrict__ A, long lda, long sA,
    const f16* __restrict__ B, long ldb, long sB,
    float* __restrict__ outF, long ldF, long sF, long sSl,
    f16* __restrict__ outH, long ldH, long sH,
    f16* __restrict__ outH2, long ldH2, long sH2,
    f16* __restrict__ out2, long ld2, long s2,
    const float* __restrict__ bias1, const float* __restrict__ bias2,
    int M, int N, int K, int act, int bmod, int zdiv, int ilv)
{
  __shared__ __align__(16) f16 As[128][40];
  __shared__ __align__(16) f16 Bs[128][40];
  const int tid = threadIdx.x;
  const int w = tid >> 6, lane = tid & 63;
  const int wm = (w & 1) * 64, wn = (w >> 1) * 64;
  const int lr = lane >> 4, lc = lane & 15;
  const long m0 = (long)blockIdx.x * 128;
  const long n0 = (long)blockIdx.y * 128;
  int z = blockIdx.z, batch = z, slice = 0, Ks = K;
  if (zdiv > 1) { batch = z / zdiv; slice = z - batch * zdiv; Ks = K / zdiv; }
  const long kbeg = (long)slice * Ks;
  A += (long)batch * sA;
  B += (long)batch * sB;

  const int rr = tid >> 2, sg = (tid & 3) * 8;
  const int nIt = Ks / 32;

  uint4 pa[2], pb[2];
  {
    long k = kbeg;
    long kb = bmod ? (k & (bmod - 1)) : k;
#pragma unroll
    for (int p = 0; p < 2; ++p) {
      int row = p * 64 + rr;
      uint4 va = {0,0,0,0}, vb = {0,0,0,0};
      if (m0 + row < M) va = *(const uint4*)(A + (m0 + row) * lda + k + sg);
      if (n0 + row < N) vb = *(const uint4*)(B + (n0 + row) * ldb + kb + sg);
      pa[p] = va; pb[p] = vb;
    }
  }

  f32x4 acc[4][4];
#pragma unroll
  for (int i = 0; i < 4; ++i)
#pragma unroll
    for (int j = 0; j < 4; ++j) { f32x4 zz = {0.f,0.f,0.f,0.f}; acc[i][j] = zz; }

  for (int it = 0; it < nIt; ++it) {
#pragma unroll
    for (int p = 0; p < 2; ++p) {
      *(uint4*)&As[p * 64 + rr][sg] = pa[p];
      *(uint4*)&Bs[p * 64 + rr][sg] = pb[p];
    }
    __syncthreads();
    if (it + 1 < nIt) {
      long k = kbeg + (long)(it + 1) * 32;
      long kb = bmod ? (k & (bmod - 1)) : k;
#pragma unroll
      for (int p = 0; p < 2; ++p) {
        int row = p * 64 + rr;
        uint4 va = {0,0,0,0}, vb = {0,0,0,0};
        if (m0 + row < M) va = *(const uint4*)(A + (m0 + row) * lda + k + sg);
        if (n0 + row < N) vb = *(const uint4*)(B + (n0 + row) * ldb + kb + sg);
        pa[p] = va; pb[p] = vb;
      }
    }
    f16x8 af[4], bf[4];
#pragma unroll
    for (int i = 0; i < 4; ++i) af[i] = *(const f16x8*)&As[wm + i*16 + lc][lr * 8];
#pragma unroll
    for (int j = 0; j < 4; ++j) bf[j] = *(const f16x8*)&Bs[wn + j*16 + lc][lr * 8];
#pragma unroll
    for (int i = 0; i < 4; ++i)
#pragma unroll
      for (int j = 0; j < 4; ++j)
        acc[i][j] = __builtin_amdgcn_mfma_f32_16x16x32_f16(af[i], bf[j], acc[i][j], 0, 0, 0);
    __syncthreads();
  }

  if (outF)  outF  += (long)batch * sF + (long)slice * sSl;
  if (outH)  outH  += (long)batch * sH;
  if (outH2) outH2 += (long)batch * sH2;
  if (out2)  out2  += (long)batch * s2;
#pragma unroll
  for (int i = 0; i < 4; ++i)
#pragma unroll
    for (int j = 0; j < 4; ++j)
#pragma unroll
      for (int r = 0; r < 4; ++r) {
        long row = m0 + wm + i * 16 + lr * 4 + r;
        long col = n0 + wn + j * 16 + lc;
        if (row < M && col < N) {
          float v = acc[i][j][r];
          if (bias1) v += bias1[col];
          if (bias2) v += bias2[col];
          if (act)   v = tanhf(v);
          if (outF) {
            long fc = ilv ? ((col & 1023) * 4 + (col >> 10)) : col;
            outF[row * ldF + fc] = v;
          }
          if (outH)  outH[row * ldH + col] = (f16)v;
          if (outH2) outH2[row * ldH2 + col] = (f16)v;
          if (out2) {
            f16 hi = (f16)v;
            out2[row * ld2 + col]        = hi;
            out2[row * ld2 + 1024 + col] = (f16)(v - (float)hi);
          }
        }
      }
}

// ---------------------------------------------------------------------------
// Persistent LSTM (R3-proven flag-gated dataflow) + hidden NL transpose.
// 256 blocks x 256 threads, 1 block/CU:
//   blocks 0..127:  the R3 LSTM (verified 495-504us across R3/R8).
//   blocks 128..255: transpose nl (B,512,1024)fp32 -> ctxT (B,H,L)f16 AND
//     ctx_h (B,L,H)f16 on the otherwise-idle half of the chip, hidden under
//     the LSTM's latency-bound shadow (R8 verified no LSTM slowdown). env
//     is transposed later by the standalone k_transpose into the SAME two
//     buffers (R3's sequential reuse -> workspace stays ~208MB; R7's 272MB
//     overflowed).
__global__ __launch_bounds__(256) void k_lstm_all(
    const f16* __restrict__ Whh,          // (4096,1024)
    const float* __restrict__ nt_table,   // (200,1024,4) gate-interleaved
    const float* __restrict__ prod_gates, // (32,1024,4) gate-interleaved
    const int* __restrict__ nt_ids,       // (128,32)
    const float* __restrict__ c0,         // (32,1024)
    f16* __restrict__ st,                 // (129,128,32,8) step/block-major
    f16* __restrict__ q2,                 // (4096,2048) hi|lo
    f16* __restrict__ X,                  // (4096,3072)
    f16* __restrict__ Y1,                 // (4096,2048)
    int* __restrict__ flags,              // 512 dense ints: [bx][wave]
    const float* __restrict__ nl,         // (32,512,1024) fp32
    f16* __restrict__ ctxT, f16* __restrict__ ctxN)
{
  __shared__ __align__(16) f16 whh_s[32][1032];
  __shared__ float partial[2][4][32][34];
  __shared__ float tile[32][33];
  const int tid = threadIdx.x;
  const int bx = blockIdx.x;

  if (bx >= 128) {
    // ---------------- nl transpose worker ----------------
    const int me = bx - 128;
    const int c = tid & 31, r = tid >> 5;
    for (int idx = me; idx < 16384; idx += 128) {
      int b = idx >> 9, rr2 = idx & 511;
      int l0 = (rr2 & 15) * 32, h0v = (rr2 >> 4) * 32;
      const float* inb = nl + (long)b * 512 * 1024;
      f16* oTb = ctxT + (long)b * 1024 * 512;
      f16* oNb = ctxN + (long)b * 512 * 1024;
#pragma unroll
      for (int p = 0; p < 4; ++p) {
        float v = inb[(long)(l0 + r + p*8) * 1024 + h0v + c];
        tile[r + p*8][c] = v;
        oNb[(long)(l0 + r + p*8) * 1024 + h0v + c] = (f16)v;
      }
      __syncthreads();
#pragma unroll
      for (int p = 0; p < 4; ++p)
        oTb[(long)(h0v + r + p*8) * 512 + l0 + c] = (f16)tile[c][r + p*8];
      __syncthreads();   // tile reused next iteration
    }
    return;
  }

  // ---------------- LSTM (identical to R3/R8) ----------------
  const int w = tid >> 6, lane = tid & 63;
  const int lr = lane >> 4, lc = lane & 15;
  const int j0 = bx * 8;

  // stage Whh slice: LDS row r=(g*8+jj) <- global row g*1024 + j0 + jj
  for (int i = tid; i < 32 * 128; i += 256) {
    int r = i >> 7, c8 = i & 127;
    int g = r >> 3, jj = r & 7;
    *(uint4*)&whh_s[r][c8 * 8] =
        *(const uint4*)(Whh + ((long)g * 1024 + j0 + jj) * 1024 + c8 * 8);
  }
  const int b_own = tid >> 3, jj_own = tid & 7;
  const int j_own = j0 + jj_own;
  float c_reg = c0[(long)b_own * 1024 + j_own];
  float4 pg4 = *(const float4*)(prod_gates + (long)b_own * 4096 + j_own * 4);
  int nid0 = nt_ids[b_own];
  float4 nt4 = *(const float4*)(nt_table + (long)nid0 * 4096 + j_own * 4);
  __syncthreads();   // whh_s ready

  // hoist step-invariant B fragments LDS -> registers (whh_s dead afterwards)
  f16x8 B0[8], B1[8];
#pragma unroll
  for (int kt = 0; kt < 8; ++kt) {
    int k = w * 256 + kt * 32 + lr * 8;
    B0[kt] = *(const f16x8*)&whh_s[lc][k];
    B1[kt] = *(const f16x8*)&whh_s[16 + lc][k];
  }

  // A base: fragment kt of wave w = st[t][w*32+kt*4+lr][lc or 16+lc][0..8)
  const f16* pA = st + (long)(w * 32 + lr) * 256 + lc * 8;
  const int* fp = flags + w * 128 + lane * 2;   // this wave's 128 producer flags

  for (int t = 0; t < TT; ++t) {
    // ---- poll producer flags (tiny, coalesced) ----
    if (t > 0) {
      int done = 0;
      while (true) {
        if (!done) {
          i32x2 ff;
          asm volatile("global_load_dwordx2 %0, %1, off sc0 sc1\n\t"
                       "s_waitcnt vmcnt(0)"
                       : "=&v"(ff) : "v"(fp) : "memory");
          done = (ff.x >= t) & (ff.y >= t);
        }
        if (__all(done)) break;
        __builtin_amdgcn_s_sleep(1);
      }
    }

    // ---- single A-burst: 16 x dwordx4 sc0 sc1 ----
    u32x4 A0[8], A1[8];
    {
      const f16* pt = pA + (long)t * 32768;
#pragma unroll
      for (int q = 0; q < 4; ++q) {
        asm volatile(
          "global_load_dwordx4 %0, %4, off sc0 sc1\n\t"
          "global_load_dwordx4 %1, %4, off offset:256 sc0 sc1\n\t"
          "global_load_dwordx4 %2, %4, off offset:2048 sc0 sc1\n\t"
          "global_load_dwordx4 %3, %4, off offset:2304 sc0 sc1"
          : "=&v"(A0[2*q]), "=&v"(A1[2*q]), "=&v"(A0[2*q+1]), "=&v"(A1[2*q+1])
          : "v"(pt + (long)q * 2048) : "memory");
      }
      asm volatile("s_waitcnt vmcnt(0)" ::: "memory");
      __builtin_amdgcn_sched_barrier(0);   // no MFMA hoist above the waitcnt
    }

    // prefetch next step's nt gates (off the critical path)
    float4 nt4n = nt4;
    if (t + 1 < TT) {
      int nidn = nt_ids[(t + 1) * 32 + b_own];
      nt4n = *(const float4*)(nt_table + (long)nidn * 4096 + j_own * 4);
    }

    f32x4 acc[2][2];
#pragma unroll
    for (int i = 0; i < 2; ++i)
#pragma unroll
      for (int j = 0; j < 2; ++j) { f32x4 zz = {0.f,0.f,0.f,0.f}; acc[i][j] = zz; }
#pragma unroll
    for (int kt = 0; kt < 8; ++kt) {
      f16x8 a0v = __builtin_bit_cast(f16x8, A0[kt]);
      f16x8 a1v = __builtin_bit_cast(f16x8, A1[kt]);
      acc[0][0] = __builtin_amdgcn_mfma_f32_16x16x32_f16(a0v, B0[kt], acc[0][0], 0, 0, 0);
      acc[0][1] = __builtin_amdgcn_mfma_f32_16x16x32_f16(a0v, B1[kt], acc[0][1], 0, 0, 0);
      acc[1][0] = __builtin_amdgcn_mfma_f32_16x16x32_f16(a1v, B0[kt], acc[1][0], 0, 0, 0);
      acc[1][1] = __builtin_amdgcn_mfma_f32_16x16x32_f16(a1v, B1[kt], acc[1][1], 0, 0, 0);
    }
    float (*pp)[32][34] = partial[t & 1];
#pragma unroll
    for (int mi = 0; mi < 2; ++mi)
#pragma unroll
      for (int ni = 0; ni < 2; ++ni)
#pragma unroll
        for (int r = 0; r < 4; ++r)
          pp[w][ni * 16 + lc][mi * 16 + lr * 4 + r] = acc[mi][ni][r];
    __syncthreads();

    // reduce 4 K-slices + LSTM cell (double-buffered partial: no 2nd barrier)
    float g4[4];
#pragma unroll
    for (int g = 0; g < 4; ++g) {
      int rrow = g * 8 + jj_own;
      g4[g] = pp[0][rrow][b_own] + pp[1][rrow][b_own] +
              pp[2][rrow][b_own] + pp[3][rrow][b_own];
    }
    float ii = sigmoidf_(g4[0] + nt4.x + pg4.x);
    float ff = sigmoidf_(g4[1] + nt4.y + pg4.y);
    float gg = tanhf(g4[2] + nt4.z + pg4.z);
    float oo = sigmoidf_(g4[3] + nt4.w + pg4.w);
    c_reg = ff * c_reg + ii * gg;
    float hn = oo * tanhf(c_reg);
    f16 hi = (f16)hn;

    // ---- publish h_{t+1}: pack 8 halves -> one dwordx4 per group ----
    if (t + 1 < TT) {
      union { f16 h; unsigned short u; } cv; cv.h = hi;
      unsigned me2 = cv.u;
      unsigned d  = me2 | ((unsigned)__shfl_down((int)me2, 1) << 16);
      unsigned d2 = (unsigned)__shfl_down((int)d, 2);
      unsigned e0 = (unsigned)__shfl_down((int)d, 4);
      unsigned e1 = (unsigned)__shfl_down((int)d2, 4);
      if (jj_own == 0) {
        u32x4 pay; pay.x = d; pay.y = d2; pay.z = e0; pay.w = e1;
        f16* pst = st + (long)(t + 1) * 32768 + bx * 256 + b_own * 8;
        asm volatile("global_store_dwordx4 %0, %1, off sc0 sc1"
                     :: "v"(pst), "v"(pay) : "memory");
      }
      asm volatile("s_waitcnt vmcnt(0)" ::: "memory");   // data acked
      if (lane == 0) {
        int* myf = flags + bx * 4 + w;
        int fv = t + 1;
        asm volatile("global_store_dword %0, %1, off sc0 sc1"
                     :: "v"(myf), "v"(fv) : "memory");
      }
    }

    // non-critical stores: complete in the shadow of the next poll
    long row = (long)b_own * 128 + t;
    q2[row * 2048 + j_own]        = hi;
    q2[row * 2048 + 1024 + j_own] = (f16)(hn - (float)hi);
    X[row * 3072 + j_own]         = hi;
    Y1[row * 2048 + 1024 + j_own] = hi;

    nt4 = nt4n;
  }
}

// ---------------------------------------------------------------------------
// Row softmax over 512 cols of sum of 4 fp32 planes -> fp16. One block/row.
__global__ __launch_bounds__(256) void k_softmax4(const float* __restrict__ p,
                                                  long pstride,
                                                  f16* __restrict__ out) {
  long row = blockIdx.x;
  const float* p0 = p + row * 512;
  out += row * 512;
  const int tid = threadIdx.x, w = tid >> 6, lane = tid & 63;
  float vx = 0.f, vy = 0.f;
#pragma unroll
  for (int s = 0; s < 4; ++s) {
    float2 a = ((const float2*)(p0 + s * pstride))[tid];
    vx += a.x; vy += a.y;
  }
  float m = fmaxf(vx, vy);
#pragma unroll
  for (int off = 32; off; off >>= 1) m = fmaxf(m, __shfl_xor(m, off));
  __shared__ float red[8];
  if (lane == 0) red[w] = m;
  __syncthreads();
  m = fmaxf(fmaxf(red[0], red[1]), fmaxf(red[2], red[3]));
  float e0 = __expf(vx - m), e1 = __expf(vy - m);
  float s2 = e0 + e1;
#pragma unroll
  for (int off = 32; off; off >>= 1) s2 += __shfl_xor(s2, off);
  if (lane == 0) red[4 + w] = s2;
  __syncthreads();
  s2 = red[4] + red[5] + red[6] + red[7];
  float inv = 1.0f / s2;
  out[tid * 2]     = (f16)(e0 * inv);
  out[tid * 2 + 1] = (f16)(e1 * inv);
}

// ---------------------------------------------------------------------------
extern "C" void kernel_launch(void* const* d_in, const int* in_sizes, int n_in,
                              void* d_out, int out_size, void* d_ws, size_t ws_size,
                              hipStream_t stream)
{
  const int*   init_prod = (const int*)d_in[0];
  const int*   nt_ids    = (const int*)d_in[1];
  const float* h0   = (const float*)d_in[2];
  const float* c0   = (const float*)d_in[3];
  const float* nl   = (const float*)d_in[4];
  const float* env  = (const float*)d_in[5];
  const float* nt_emb   = (const float*)d_in[6];
  const float* rule_emb = (const float*)d_in[7];
  const float* W_ih = (const float*)d_in[8];
  const float* W_hh = (const float*)d_in[9];
  const float* b_ih = (const float*)d_in[10];
  const float* b_hh = (const float*)d_in[11];
  const float* Wz   = (const float*)d_in[12];
  const float* bz   = (const float*)d_in[13];
  const float* We   = (const float*)d_in[14];
  const float* be   = (const float*)d_in[15];
  const float* Wc   = (const float*)d_in[16];
  const float* bc   = (const float*)d_in[17];
  float* out = (float*)d_out;
  (void)in_sizes; (void)n_in; (void)out_size; (void)ws_size;

  size_t off = 0;
  auto carve = [&](size_t bytes) {
    char* p = (char*)d_ws + off;
    off += (bytes + 255) & ~(size_t)255;
    return (void*)p;
  };
  // Total carve ~208 MB -- the R3/R5/R8 proven-safe workspace envelope.
  f16*   Whh_h   = (f16*)carve(4096L * 1024 * 2);
  f16*   Wz_h    = (f16*)carve(1024L * 2048 * 2);
  f16*   We_h    = (f16*)carve(1024L * 2048 * 2);
  f16*   Wc_h    = (f16*)carve(1024L * 3072 * 2);
  f16*   nte_h   = (f16*)carve(200L * 1024 * 2);
  f16*   prod_h  = (f16*)carve(32L * 1024 * 2);
  float* nt_table   = (float*)carve(200L * 4096 * 4);   // gate-interleaved
  float* prod_gates = (float*)carve(32L * 4096 * 4);    // gate-interleaved
  f16*   st_hi   = (f16*)carve(129L * 128 * 32 * 8 * 2);  // [t][bx][b][jj]
  f16*   q2      = (f16*)carve(4096L * 2048 * 2);   // query hi|lo (h, then zt)
  f16*   X       = (f16*)carve(4096L * 3072 * 2);   // [h | zt | et] for ct GEMM
  f16*   Y1      = (f16*)carve(4096L * 2048 * 2);   // [mix1 | h]  for zt GEMM
  f16*   Y2      = (f16*)carve(4096L * 2048 * 2);   // [mix2 | zt] for et GEMM
  f16*   ctx_h   = (f16*)carve(32L * 512 * 1024 * 2);   // shared nl->env
  f16*   ctxT    = (f16*)carve(32L * 1024 * 512 * 2);   // shared nl->env
  float* scoresP = (float*)carve(4L * 32 * 128 * 512 * 4);  // 4 split-K planes
  f16*   attn    = (f16*)carve(4096L * 512 * 2);
  int*   bar     = (int*)carve(2048);   // 512 dense flags
  f16*   Wih_h   = (f16*)X;   // alias: Wih dead before LSTM writes X

  // fused prep: converts + gather + h0 seed + flag zero (one launch)
  k_prep<<<dim3(8192), dim3(256), 0, stream>>>(
      W_ih, W_hh, Wz, We, Wc, nt_emb, rule_emb, init_prod, h0,
      Wih_h, Whh_h, Wz_h, We_h, Wc_h, nte_h, prod_h, st_hi, bar);

  auto gemm = [&](const f16* A, long lda, long sA,
                  const f16* B, long ldb, long sB,
                  float* oF, long ldF, long sF, long sSl,
                  f16* oH, long ldH, long sH,
                  f16* oH2, long ldH2, long sH2,
                  f16* o2, long ld2, long s2,
                  const float* b1, const float* b2,
                  int M, int N, int K, int act, int bmod, int zdiv, int ilv,
                  int batch) {
    dim3 grid((unsigned)((M + 127) / 128), (unsigned)((N + 127) / 128),
              (unsigned)(batch * zdiv));
    k_gemm<<<grid, dim3(256), 0, stream>>>(A, lda, sA, B, ldb, sB,
                                           oF, ldF, sF, sSl, oH, ldH, sH,
                                           oH2, ldH2, sH2, o2, ld2, s2,
                                           b1, b2, M, N, K, act, bmod, zdiv, ilv);
  };
  const long SPL = 32L * 128 * 512;   // split-K plane stride (floats)

  // gate tables (gate-interleaved fp32 layout via ilv=1)
  gemm(nte_h, 1024, 0, Wih_h, 2048, 0, nt_table, 4096, 0, 0,
       nullptr,0,0, nullptr,0,0, nullptr,0,0, nullptr, nullptr,
       200, 4096, 1024, 0, 0, 1, 1, 1);
  gemm(prod_h, 1024, 0, Wih_h + 1024, 2048, 0, prod_gates, 4096, 0, 0,
       nullptr,0,0, nullptr,0,0, nullptr,0,0, b_ih, b_hh,
       32, 4096, 1024, 0, 0, 1, 1, 1);

  // persistent LSTM (blocks 0-127) + hidden nl transpose (blocks 128-255)
  k_lstm_all<<<dim3(256), dim3(256), 0, stream>>>(
      Whh_h, nt_table, prod_gates, nt_ids, c0, st_hi, q2, X, Y1, bar,
      nl, ctxT, ctx_h);

  // --- attention over nl (ctx buffers already filled by the fused kernel) ---
  gemm(q2, 2048, 128L * 2048, ctx_h, 1024, 512L * 1024,
       scoresP, 512, 128L * 512, SPL, nullptr,0,0, nullptr,0,0, nullptr,0,0,
       nullptr, nullptr, 128, 512, 2048, 0, 1024, 4, 0, 32);
  k_softmax4<<<dim3(4096), dim3(256), 0, stream>>>(scoresP, SPL, attn);
  gemm(attn, 512, 128L * 512, ctxT, 512, 1024L * 512,
       nullptr,0,0,0, Y1, 2048, 128L * 2048, nullptr,0,0, nullptr,0,0,
       nullptr, nullptr, 128, 1024, 512, 0, 0, 1, 0, 32);
  // zt = tanh(Y1=[mix1|h] @ Wz^T + bz) -> X[:,1024:2048), Y2[:,1024:2048), q2
  gemm(Y1, 2048, 0, Wz_h, 2048, 0,
       nullptr,0,0,0, X + 1024, 3072, 0, Y2 + 1024, 2048, 0, q2, 2048, 0,
       bz, nullptr, 4096, 1024, 2048, 1, 0, 1, 0, 1);

  // --- attention over env (sequential reuse of ctx buffers, R3 pattern) ---
  k_transpose<<<dim3(16, 32, 32), dim3(256), 0, stream>>>(env, ctxT, ctx_h);
  gemm(q2, 2048, 128L * 2048, ctx_h, 1024, 512L * 1024,
       scoresP, 512, 128L * 512, SPL, nullptr,0,0, nullptr,0,0, nullptr,0,0,
       nullptr, nullptr, 128, 512, 2048, 0, 1024, 4, 0, 32);
  k_softmax4<<<dim3(4096), dim3(256), 0, stream>>>(scoresP, SPL, attn);
  gemm(attn, 512, 128L * 512, ctxT, 512, 1024L * 512,
       nullptr,0,0,0, Y2, 2048, 128L * 2048, nullptr,0,0, nullptr,0,0,
       nullptr, nullptr, 128, 1024, 512, 0, 0, 1, 0, 32);
  // et = tanh(Y2=[mix2|zt] @ We^T + be) -> X[:,2048:3072)
  gemm(Y2, 2048, 0, We_h, 2048, 0,
       nullptr,0,0,0, X + 2048, 3072, 0, nullptr,0,0, nullptr,0,0,
       be, nullptr, 4096, 1024, 2048, 1, 0, 1, 0, 1);

  // --- ct = tanh(X=[h|zt|et] @ Wc^T + bc) -> d_out (T,B,H) ---
  gemm(X, 3072, 128L * 3072, Wc_h, 3072, 0,
       out, 32L * 1024, 1024, 0, nullptr,0,0, nullptr,0,0, nullptr,0,0,
       bc, nullptr, 128, 1024, 3072, 1, 0, 1, 0, 32);
}